// Round 11
// baseline (613.491 us; speedup 1.0000x reference)
//
#include <hip/hip_runtime.h>

#define E_CNT 500000
#define N_CNT 50000
#define DD 128
#define HH 256
#define LN_EPS 1e-5f

typedef __attribute__((ext_vector_type(8))) short bh8;   // 8 x bf16 (MFMA A/B frag)
typedef __attribute__((ext_vector_type(4))) float fx4;   // MFMA C/D frag

__device__ __forceinline__ float b2f(short s) {
    return __uint_as_float(((unsigned)(unsigned short)s) << 16);
}
__device__ __forceinline__ short f2b(float f) {
    unsigned x = __float_as_uint(f);
    x += 0x7fffu + ((x >> 16) & 1u);   // RNE
    return (short)(x >> 16);
}
__device__ __forceinline__ fx4 mfma16(bh8 a, bh8 b, fx4 c) {
    return __builtin_amdgcn_mfma_f32_16x16x32_bf16(a, b, c, 0, 0, 0);
}
__device__ __forceinline__ int swz128(int row, int k) {   // [*][128] bf16 tile
    return ((row * 128 + k) * 2) ^ ((row & 7) << 4);
}
__device__ __forceinline__ int swz256(int row, int c) {   // [*][256] bf16 tile
    return ((row * 256 + c) * 2) ^ ((row & 7) << 4);
}
__device__ __forceinline__ bh8 pack8(const float* s) {
    float4 f0 = *(const float4*)s, f1 = *(const float4*)(s + 4);
    bh8 v;
    v[0] = f2b(f0.x); v[1] = f2b(f0.y); v[2] = f2b(f0.z); v[3] = f2b(f0.w);
    v[4] = f2b(f1.x); v[5] = f2b(f1.y); v[6] = f2b(f1.z); v[7] = f2b(f1.w);
    return v;
}

// ---------------------------------------------------------------------------
// Weight transpose-convert: dst[n][k] = bf16(src[k][n]); src is [K][N] f32.
// ---------------------------------------------------------------------------
__global__ void wtrans(const float* __restrict__ src, short* __restrict__ dst,
                       int K, int N) {
    int idx = blockIdx.x * 256 + threadIdx.x;
    if (idx >= K * N) return;
    int n = idx / K, k = idx - n * K;
    dst[idx] = f2b(src[(size_t)k * N + n]);
}

// packed GEMM1 B for edge kernel: eW1a[n][k] = bf16(eW1[k][n]), k<128
__global__ void wtransA(const float* __restrict__ src, short* __restrict__ dst) {
    int idx = blockIdx.x * 256 + threadIdx.x;
    if (idx >= 256 * 128) return;
    int n = idx >> 7, k = idx & 127;
    dst[idx] = f2b(src[(size_t)k * 256 + n]);
}

// ---------------------------------------------------------------------------
// Table precompute: tabS[n][h] = bf16(nodes[n]@eW1[128:256]),
//                   tabR[n][h] = bf16(nodes[n]@eW1[256:384]).
// ---------------------------------------------------------------------------
__launch_bounds__(512, 2)
__global__ void table_kernel(const float* __restrict__ nodes,
                             const short* __restrict__ eW1t,   // [256][384]
                             short* __restrict__ tabS, short* __restrict__ tabR) {
    __shared__ char Abuf[128 * 128 * 2];
    const int tid = threadIdx.x;
    const int l = tid & 63, wid = tid >> 6;
    const int wm = wid >> 2, wn = wid & 3;
    const int n0 = blockIdx.x * 128;

    for (int it = 0; it < 4; ++it) {
        int c = tid + 512 * it;
        int row = c >> 4, cc = (c & 15) * 8;
        int n = n0 + row; if (n >= N_CNT) n = N_CNT - 1;
        *(bh8*)(Abuf + swz128(row, cc)) = pack8(nodes + (size_t)n * DD + cc);
    }
    __syncthreads();

    fx4 accS[4][4] = {}; fx4 accR[4][4] = {};
    #pragma unroll
    for (int kk = 0; kk < 4; ++kk) {
        int krow = kk * 32 + (l >> 4) * 8;
        bh8 a[4], bs[4], br[4];
        #pragma unroll
        for (int i = 0; i < 4; ++i)
            a[i] = *(const bh8*)(Abuf + swz128(wm * 64 + 16 * i + (l & 15), krow));
        #pragma unroll
        for (int j = 0; j < 4; ++j) {
            const short* bp = eW1t + (size_t)(wn * 64 + 16 * j + (l & 15)) * 384 + krow;
            bs[j] = *(const bh8*)(bp + 128);
            br[j] = *(const bh8*)(bp + 256);
        }
        #pragma unroll
        for (int i = 0; i < 4; ++i)
            #pragma unroll
            for (int j = 0; j < 4; ++j) {
                accS[i][j] = mfma16(a[i], bs[j], accS[i][j]);
                accR[i][j] = mfma16(a[i], br[j], accR[i][j]);
            }
    }
    #pragma unroll
    for (int i = 0; i < 4; ++i)
        #pragma unroll
        for (int r = 0; r < 4; ++r) {
            int row = wm * 64 + 16 * i + (l >> 4) * 4 + r;
            int n = n0 + row;
            if (n < N_CNT) {
                #pragma unroll
                for (int j = 0; j < 4; ++j) {
                    int col = wn * 64 + 16 * j + (l & 15);
                    tabS[(size_t)n * HH + col] = f2b(accS[i][j][r]);
                    tabR[(size_t)n * HH + col] = f2b(accR[i][j][r]);
                }
            }
        }
}

// ---------------------------------------------------------------------------
// Edge kernel v11 = v10 + packed-bf16 atomics (global_atomic_pk_add_bf16):
// halves atomic instruction count (64M->32M) and RMW bytes (244->122MB).
// agg is now bf16 [N][128]; node kernel consumes it directly (no f2b).
// ---------------------------------------------------------------------------
__launch_bounds__(256, 4)
__global__ void edge_kernel(const float* __restrict__ edges,
                            const int* __restrict__ senders,
                            const int* __restrict__ receivers,
                            const short* __restrict__ tabS,
                            const short* __restrict__ tabR,
                            const short* __restrict__ eW1a,   // [256][128]
                            const short* __restrict__ eW2t,   // [128][256]
                            const float* __restrict__ eb1,
                            const float* __restrict__ eg,
                            const float* __restrict__ ebt,
                            const float* __restrict__ eb2,
                            short* __restrict__ aggBF,        // [N][128] bf16
                            float* __restrict__ edges_out) {
    __shared__ short Abuf[32 * 128];     //  8KB edges tile (bf16, swizzled)
    __shared__ short Sbuf[32 * 256];     // 16KB table-sum, later H
    __shared__ float P[32][4][2];        //  1KB LN partials
    __shared__ int irecv[32];

    const int tid = threadIdx.x;
    const int l = tid & 63, wid = tid >> 6, lg = l >> 4, lo = l & 15;
    const int e0 = blockIdx.x * 32;

    if (tid < 32) {
        int e = e0 + tid; if (e >= E_CNT) e = E_CNT - 1;
        irecv[tid] = receivers[e];
    }

    // ---- stage A: 32 rows x 128 cols; 512 chunks / 256 thr = 2 each ----
    #pragma unroll
    for (int it = 0; it < 2; ++it) {
        int ch = tid + 256 * it;
        int row = ch >> 4, c = (ch & 15) * 8;
        int e = e0 + row; if (e >= E_CNT) e = E_CNT - 1;
        *(bh8*)((char*)Abuf + swz128(row, c)) = pack8(edges + (size_t)e * DD + c);
    }
    // ---- issue table gathers into regs (consumed after GEMM1) ----
    bh8 ts[4], tr[4];
    #pragma unroll
    for (int it = 0; it < 4; ++it) {
        int ch = tid + 256 * it;                 // 1024 chunks of 8 bf16
        int row = ch >> 5, cc = (ch & 31) * 8;
        int e = e0 + row; if (e >= E_CNT) e = E_CNT - 1;
        ts[it] = *(const bh8*)(tabS + (size_t)senders[e] * HH + cc);
        tr[it] = *(const bh8*)(tabR + (size_t)receivers[e] * HH + cc);
    }
    __syncthreads();

    // ---- GEMM1: A[32x128] @ W1a -> acc[32x256]; wave = 32 rows x 64 cols ----
    const int wn = wid;                          // 4 waves = 4 col groups
    fx4 acc[2][4] = {};
    #pragma unroll
    for (int kk = 0; kk < 4; ++kk) {
        int krow = kk * 32 + lg * 8;
        bh8 a[2], b[4];
        #pragma unroll
        for (int i = 0; i < 2; ++i)
            a[i] = *(const bh8*)((char*)Abuf + swz128(16 * i + lo, krow));
        #pragma unroll
        for (int j = 0; j < 4; ++j)
            b[j] = *(const bh8*)(eW1a + (size_t)(wn * 64 + 16 * j + lo) * 128 + krow);
        #pragma unroll
        for (int i = 0; i < 2; ++i)
            #pragma unroll
            for (int j = 0; j < 4; ++j)
                acc[i][j] = mfma16(a[i], b[j], acc[i][j]);
    }

    // ---- combine gathered tables -> Sbuf ----
    #pragma unroll
    for (int it = 0; it < 4; ++it) {
        int ch = tid + 256 * it;
        int row = ch >> 5, cc = (ch & 31) * 8;
        bh8 v;
        #pragma unroll
        for (int q = 0; q < 8; ++q) v[q] = f2b(b2f(ts[it][q]) + b2f(tr[it][q]));
        *(bh8*)((char*)Sbuf + swz256(row, cc)) = v;
    }
    __syncthreads();

    // ---- epilogue 1: + table-sum + eb1, LN partials ----
    float eb1c[4], egc[4], ebtc[4];
    #pragma unroll
    for (int j = 0; j < 4; ++j) {
        int col = wn * 64 + 16 * j + lo;
        eb1c[j] = eb1[col]; egc[j] = eg[col]; ebtc[j] = ebt[col];
    }
    #pragma unroll
    for (int i = 0; i < 2; ++i)
        #pragma unroll
        for (int r = 0; r < 4; ++r) {
            int row = 16 * i + lg * 4 + r;
            float s = 0.f, q = 0.f;
            #pragma unroll
            for (int j = 0; j < 4; ++j) {
                int col = wn * 64 + 16 * j + lo;
                float v = acc[i][j][r] + eb1c[j] +
                          b2f(*(const short*)((char*)Sbuf + swz256(row, col)));
                acc[i][j][r] = v;
                s += v; q += v * v;
            }
            #pragma unroll
            for (int m = 1; m < 16; m <<= 1) {
                s += __shfl_xor(s, m);
                q += __shfl_xor(q, m);
            }
            if (lo == 0) { P[row][wn][0] = s; P[row][wn][1] = q; }
        }
    __syncthreads();   // Sbuf reads done; partials visible

    // ---- epilogue 2: LN + relu -> H into Sbuf (same-thread cells) ----
    #pragma unroll
    for (int i = 0; i < 2; ++i)
        #pragma unroll
        for (int r = 0; r < 4; ++r) {
            int row = 16 * i + lg * 4 + r;
            float s = P[row][0][0] + P[row][1][0] + P[row][2][0] + P[row][3][0];
            float q = P[row][0][1] + P[row][1][1] + P[row][2][1] + P[row][3][1];
            float mean = s * (1.0f / 256.0f);
            float var = q * (1.0f / 256.0f) - mean * mean;
            float rstd = rsqrtf(var + LN_EPS);
            #pragma unroll
            for (int j = 0; j < 4; ++j) {
                int col = wn * 64 + 16 * j + lo;
                float v = (acc[i][j][r] - mean) * rstd * egc[j] + ebtc[j];
                v = fmaxf(v, 0.0f);
                *(short*)((char*)Sbuf + swz256(row, col)) = f2b(v);
            }
        }
    __syncthreads();

    // ---- GEMM2: H[32x256] @ eW2 -> [32x128]; wave = 16 rows x 64 cols ----
    const int wm2 = wid >> 1, wn2 = wid & 1;
    fx4 acc2[4] = {};
    #pragma unroll
    for (int kk = 0; kk < 8; ++kk) {
        int krow = kk * 32 + lg * 8;
        bh8 a = *(const bh8*)((char*)Sbuf + swz256(wm2 * 16 + lo, krow));
        #pragma unroll
        for (int j = 0; j < 4; ++j) {
            bh8 b = *(const bh8*)(eW2t + (size_t)(wn2 * 64 + 16 * j + lo) * HH + krow);
            acc2[j] = mfma16(a, b, acc2[j]);
        }
    }
    float eb2c[4];
    #pragma unroll
    for (int j = 0; j < 4; ++j) eb2c[j] = eb2[wn2 * 64 + 16 * j + lo];
    #pragma unroll
    for (int r = 0; r < 4; ++r) {
        int row = wm2 * 16 + lg * 4 + r;
        int e = e0 + row;
        int rcv = irecv[row];
        #pragma unroll
        for (int j = 0; j < 4; ++j) {
            int col = wn2 * 64 + 16 * j + lo;
            float upd = acc2[j][r] + eb2c[j];
            // pair-exchange for packed atomic: adjacent cols sit in lane^1
            float par = __shfl_xor(upd, 1);
            if (e < E_CNT) {
                float res = b2f(*(const short*)((char*)Abuf + swz128(row, col)));
                edges_out[(size_t)e * DD + col] = upd + res;
                if ((lo & 1) == 0) {
                    // even lane owns cols (col, col+1) = (upd, par)
                    unsigned pk = ((unsigned)(unsigned short)f2b(upd)) |
                                  (((unsigned)(unsigned short)f2b(par)) << 16);
                    short* p = aggBF + (size_t)rcv * DD + col;
                    asm volatile("global_atomic_pk_add_bf16 %0, %1, off"
                                 :: "v"(p), "v"(pk) : "memory");
                }
            }
        }
    }
}

// ---------------------------------------------------------------------------
// Node kernel: nx=[nodes|aggBF] -> GEMM1 (K=256) -> LN/relu -> GEMM2 + nb2 + nodes
// aggBF consumed directly as bf16 (no conversion).
// ---------------------------------------------------------------------------
__launch_bounds__(512, 2)
__global__ void node_kernel(const float* __restrict__ nodes,
                            const short* __restrict__ aggBF,  // [N][128] bf16
                            const short* __restrict__ nW1t,   // [256][256]
                            const short* __restrict__ nW2t,   // [128][256]
                            const float* __restrict__ nb1,
                            const float* __restrict__ ng,
                            const float* __restrict__ nbt,
                            const float* __restrict__ nb2,
                            float* __restrict__ nodes_out) {
    __shared__ char X[64 * 256 * 2];
    __shared__ float P[64][4][2];

    const int tid = threadIdx.x;
    const int l = tid & 63, wid = tid >> 6;
    const int n0 = blockIdx.x * 64;

    #pragma unroll
    for (int it = 0; it < 4; ++it) {
        int c = tid + 512 * it;
        int row = c >> 5, cc = (c & 31) * 8;
        int n = n0 + row; if (n >= N_CNT) n = N_CNT - 1;
        bh8 v;
        if (cc < DD) v = pack8(nodes + (size_t)n * DD + cc);
        else         v = *(const bh8*)(aggBF + (size_t)n * DD + (cc - DD));
        *(bh8*)(X + swz256(row, cc)) = v;
    }
    __syncthreads();

    const int wm = wid >> 2, wn = wid & 3;
    fx4 acc[2][4] = {};
    #pragma unroll
    for (int kk = 0; kk < 8; ++kk) {
        int krow = kk * 32 + (l >> 4) * 8;
        bh8 a[2], b[4];
        #pragma unroll
        for (int i = 0; i < 2; ++i)
            a[i] = *(const bh8*)(X + swz256(wm * 32 + 16 * i + (l & 15), krow));
        #pragma unroll
        for (int j = 0; j < 4; ++j)
            b[j] = *(const bh8*)(nW1t + (size_t)(wn * 64 + 16 * j + (l & 15)) * 256 + krow);
        #pragma unroll
        for (int i = 0; i < 2; ++i)
            #pragma unroll
            for (int j = 0; j < 4; ++j)
                acc[i][j] = mfma16(a[i], b[j], acc[i][j]);
    }
    __syncthreads();

    float nb1c[4], ngc[4], nbtc[4];
    #pragma unroll
    for (int j = 0; j < 4; ++j) {
        int col = wn * 64 + 16 * j + (l & 15);
        nb1c[j] = nb1[col]; ngc[j] = ng[col]; nbtc[j] = nbt[col];
    }
    #pragma unroll
    for (int i = 0; i < 2; ++i)
        #pragma unroll
        for (int r = 0; r < 4; ++r) {
            int row = wm * 32 + 16 * i + (l >> 4) * 4 + r;
            float s = 0.f, q = 0.f;
            #pragma unroll
            for (int j = 0; j < 4; ++j) {
                float v = acc[i][j][r] + nb1c[j];
                acc[i][j][r] = v;
                s += v; q += v * v;
            }
            #pragma unroll
            for (int m = 1; m < 16; m <<= 1) {
                s += __shfl_xor(s, m);
                q += __shfl_xor(q, m);
            }
            if ((l & 15) == 0) { P[row][wn][0] = s; P[row][wn][1] = q; }
        }
    __syncthreads();

    #pragma unroll
    for (int i = 0; i < 2; ++i)
        #pragma unroll
        for (int r = 0; r < 4; ++r) {
            int row = wm * 32 + 16 * i + (l >> 4) * 4 + r;
            float s = P[row][0][0] + P[row][1][0] + P[row][2][0] + P[row][3][0];
            float q = P[row][0][1] + P[row][1][1] + P[row][2][1] + P[row][3][1];
            float mean = s * (1.0f / 256.0f);
            float var = q * (1.0f / 256.0f) - mean * mean;
            float rstd = rsqrtf(var + LN_EPS);
            #pragma unroll
            for (int j = 0; j < 4; ++j) {
                int col = wn * 64 + 16 * j + (l & 15);
                float v = (acc[i][j][r] - mean) * rstd * ngc[j] + nbtc[j];
                v = fmaxf(v, 0.0f);
                *(short*)(X + swz256(row, col)) = f2b(v);
            }
        }
    __syncthreads();

    const int wm2 = wid >> 1, wn2 = wid & 1;
    fx4 acc2[4] = {};
    #pragma unroll
    for (int kk = 0; kk < 8; ++kk) {
        int krow = kk * 32 + (l >> 4) * 8;
        bh8 a = *(const bh8*)(X + swz256(wm2 * 16 + (l & 15), krow));
        #pragma unroll
        for (int j = 0; j < 4; ++j) {
            bh8 b = *(const bh8*)(nW2t + (size_t)(wn2 * 64 + 16 * j + (l & 15)) * 256 + krow);
            acc2[j] = mfma16(a, b, acc2[j]);
        }
    }
    float nb2c[4];
    #pragma unroll
    for (int j = 0; j < 4; ++j) nb2c[j] = nb2[wn2 * 64 + 16 * j + (l & 15)];
    #pragma unroll
    for (int r = 0; r < 4; ++r) {
        int row = wm2 * 16 + (l >> 4) * 4 + r;
        int n = n0 + row;
        if (n < N_CNT) {
            #pragma unroll
            for (int j = 0; j < 4; ++j) {
                int col = wn2 * 64 + 16 * j + (l & 15);
                nodes_out[(size_t)n * DD + col] =
                    acc2[j][r] + nb2c[j] + nodes[(size_t)n * DD + col];
            }
        }
    }
}

// ---------------------------------------------------------------------------
extern "C" void kernel_launch(void* const* d_in, const int* in_sizes, int n_in,
                              void* d_out, int out_size, void* d_ws, size_t ws_size,
                              hipStream_t stream) {
    const float* nodes = (const float*)d_in[0];
    const float* edges = (const float*)d_in[1];
    const int* senders = (const int*)d_in[2];
    const int* receivers = (const int*)d_in[3];
    const float* eW1 = (const float*)d_in[4];
    const float* eb1 = (const float*)d_in[5];
    const float* eg  = (const float*)d_in[6];
    const float* ebt = (const float*)d_in[7];
    const float* eW2 = (const float*)d_in[8];
    const float* eb2 = (const float*)d_in[9];
    const float* nW1 = (const float*)d_in[10];
    const float* nb1 = (const float*)d_in[11];
    const float* ng  = (const float*)d_in[12];
    const float* nbt = (const float*)d_in[13];
    const float* nW2 = (const float*)d_in[14];
    const float* nb2 = (const float*)d_in[15];

    char* ws = (char*)d_ws;
    short* aggBF = (short*)(ws + 0);            // 12,800,000 B [N][128] bf16
    short* eW1t  = (short*)(ws + 12800000);     //    196,608 B [256][384]
    short* eW2t  = (short*)(ws + 12996608);     //     65,536 B [128][256]
    short* nW1t  = (short*)(ws + 13062144);     //    131,072 B [256][256]
    short* nW2t  = (short*)(ws + 13193216);     //     65,536 B [128][256]
    short* eW1a  = (short*)(ws + 13258752);     //     65,536 B [256][128]
    short* tabS  = (short*)(ws + 13324288);     // 25,600,000 B [N][256]
    short* tabR  = (short*)(ws + 38924288);     // 25,600,000 B [N][256]

    float* nodes_out = (float*)d_out;
    float* edges_out = nodes_out + (size_t)N_CNT * DD;

    hipMemsetAsync(aggBF, 0, (size_t)N_CNT * DD * sizeof(short), stream);

    wtrans<<<(384 * 256 + 255) / 256, 256, 0, stream>>>(eW1, eW1t, 384, 256);
    wtrans<<<(256 * 128 + 255) / 256, 256, 0, stream>>>(eW2, eW2t, 256, 128);
    wtrans<<<(256 * 256 + 255) / 256, 256, 0, stream>>>(nW1, nW1t, 256, 256);
    wtrans<<<(256 * 128 + 255) / 256, 256, 0, stream>>>(nW2, nW2t, 256, 128);
    wtransA<<<(256 * 128 + 255) / 256, 256, 0, stream>>>(eW1, eW1a);

    table_kernel<<<(N_CNT + 127) / 128, 512, 0, stream>>>(nodes, eW1t, tabS, tabR);

    edge_kernel<<<(E_CNT + 31) / 32, 256, 0, stream>>>(
        edges, senders, receivers, tabS, tabR, eW1a, eW2t,
        eb1, eg, ebt, eb2, aggBF, edges_out);

    node_kernel<<<(N_CNT + 63) / 64, 512, 0, stream>>>(
        nodes, aggBF, nW1t, nW2t, nb1, ng, nbt, nb2, nodes_out);
}

// Round 12
// 612.247 us; speedup vs baseline: 1.0020x; 1.0020x over previous
//
#include <hip/hip_runtime.h>
#include <hip/hip_bf16.h>

#define E_CNT 500000
#define N_CNT 50000
#define DD 128
#define HH 256
#define LN_EPS 1e-5f

typedef __attribute__((ext_vector_type(8))) short bh8;   // 8 x bf16 (MFMA A/B frag)
typedef __attribute__((ext_vector_type(4))) float fx4;   // MFMA C/D frag

__device__ __forceinline__ float b2f(short s) {
    return __uint_as_float(((unsigned)(unsigned short)s) << 16);
}
// paired f32->bf16 RNE via v_cvt_pk_bf16_f32 (1 instr / 2 values)
__device__ __forceinline__ unsigned f2b2(float lo, float hi) {
    float2 t; t.x = lo; t.y = hi;
    __hip_bfloat162 h2 = __float22bfloat162_rn(t);
    union { __hip_bfloat162 h; unsigned u; } cv; cv.h = h2; return cv.u;
}
__device__ __forceinline__ short f2b(float f) {   // scalar fallback (cold paths)
    unsigned x = __float_as_uint(f);
    x += 0x7fffu + ((x >> 16) & 1u);   // RNE
    return (short)(x >> 16);
}
__device__ __forceinline__ fx4 mfma16(bh8 a, bh8 b, fx4 c) {
    return __builtin_amdgcn_mfma_f32_16x16x32_bf16(a, b, c, 0, 0, 0);
}
__device__ __forceinline__ int swz128(int row, int k) {   // [*][128] bf16 tile
    return ((row * 128 + k) * 2) ^ ((row & 7) << 4);
}
__device__ __forceinline__ int swz256(int row, int c) {   // [*][256] bf16 tile
    return ((row * 256 + c) * 2) ^ ((row & 7) << 4);
}
__device__ __forceinline__ bh8 pack8(const float* s) {
    float4 f0 = *(const float4*)s, f1 = *(const float4*)(s + 4);
    union { unsigned u[4]; bh8 v; } cv;
    cv.u[0] = f2b2(f0.x, f0.y);
    cv.u[1] = f2b2(f0.z, f0.w);
    cv.u[2] = f2b2(f1.x, f1.y);
    cv.u[3] = f2b2(f1.z, f1.w);
    return cv.v;
}

// ---------------------------------------------------------------------------
// Weight transpose-convert: dst[n][k] = bf16(src[k][n]); src is [K][N] f32.
// ---------------------------------------------------------------------------
__global__ void wtrans(const float* __restrict__ src, short* __restrict__ dst,
                       int K, int N) {
    int idx = blockIdx.x * 256 + threadIdx.x;
    if (idx >= K * N) return;
    int n = idx / K, k = idx - n * K;
    dst[idx] = f2b(src[(size_t)k * N + n]);
}

// packed GEMM1 B for edge kernel: eW1a[n][k] = bf16(eW1[k][n]), k<128
__global__ void wtransA(const float* __restrict__ src, short* __restrict__ dst) {
    int idx = blockIdx.x * 256 + threadIdx.x;
    if (idx >= 256 * 128) return;
    int n = idx >> 7, k = idx & 127;
    dst[idx] = f2b(src[(size_t)k * 256 + n]);
}

// ---------------------------------------------------------------------------
// Table precompute: tabS[n][h] = bf16(nodes[n]@eW1[128:256]),
//                   tabR[n][h] = bf16(nodes[n]@eW1[256:384]).
// ---------------------------------------------------------------------------
__launch_bounds__(512, 2)
__global__ void table_kernel(const float* __restrict__ nodes,
                             const short* __restrict__ eW1t,   // [256][384]
                             short* __restrict__ tabS, short* __restrict__ tabR) {
    __shared__ char Abuf[128 * 128 * 2];
    const int tid = threadIdx.x;
    const int l = tid & 63, wid = tid >> 6;
    const int wm = wid >> 2, wn = wid & 3;
    const int n0 = blockIdx.x * 128;

    for (int it = 0; it < 4; ++it) {
        int c = tid + 512 * it;
        int row = c >> 4, cc = (c & 15) * 8;
        int n = n0 + row; if (n >= N_CNT) n = N_CNT - 1;
        *(bh8*)(Abuf + swz128(row, cc)) = pack8(nodes + (size_t)n * DD + cc);
    }
    __syncthreads();

    fx4 accS[4][4] = {}; fx4 accR[4][4] = {};
    #pragma unroll
    for (int kk = 0; kk < 4; ++kk) {
        int krow = kk * 32 + (l >> 4) * 8;
        bh8 a[4], bs[4], br[4];
        #pragma unroll
        for (int i = 0; i < 4; ++i)
            a[i] = *(const bh8*)(Abuf + swz128(wm * 64 + 16 * i + (l & 15), krow));
        #pragma unroll
        for (int j = 0; j < 4; ++j) {
            const short* bp = eW1t + (size_t)(wn * 64 + 16 * j + (l & 15)) * 384 + krow;
            bs[j] = *(const bh8*)(bp + 128);
            br[j] = *(const bh8*)(bp + 256);
        }
        #pragma unroll
        for (int i = 0; i < 4; ++i)
            #pragma unroll
            for (int j = 0; j < 4; ++j) {
                accS[i][j] = mfma16(a[i], bs[j], accS[i][j]);
                accR[i][j] = mfma16(a[i], br[j], accR[i][j]);
            }
    }
    #pragma unroll
    for (int i = 0; i < 4; ++i)
        #pragma unroll
        for (int r = 0; r < 4; ++r) {
            int row = wm * 64 + 16 * i + (l >> 4) * 4 + r;
            int n = n0 + row;
            if (n < N_CNT) {
                unsigned s01 = f2b2(accS[i][0][r], accS[i][1][r]);
                unsigned s23 = f2b2(accS[i][2][r], accS[i][3][r]);
                unsigned r01 = f2b2(accR[i][0][r], accR[i][1][r]);
                unsigned r23 = f2b2(accR[i][2][r], accR[i][3][r]);
                size_t base = (size_t)n * HH + (l & 15);
                tabS[base + wn * 64 +  0] = (short)s01;
                tabS[base + wn * 64 + 16] = (short)(s01 >> 16);
                tabS[base + wn * 64 + 32] = (short)s23;
                tabS[base + wn * 64 + 48] = (short)(s23 >> 16);
                tabR[base + wn * 64 +  0] = (short)r01;
                tabR[base + wn * 64 + 16] = (short)(r01 >> 16);
                tabR[base + wn * 64 + 32] = (short)r23;
                tabR[base + wn * 64 + 48] = (short)(r23 >> 16);
            }
        }
}

// ---------------------------------------------------------------------------
// Edge kernel v12 = v11 with all bf16 conversions via v_cvt_pk_bf16_f32
// (paired f2b2) instead of 5-op integer RNE. Structure unchanged.
// ---------------------------------------------------------------------------
__launch_bounds__(256, 4)
__global__ void edge_kernel(const float* __restrict__ edges,
                            const int* __restrict__ senders,
                            const int* __restrict__ receivers,
                            const short* __restrict__ tabS,
                            const short* __restrict__ tabR,
                            const short* __restrict__ eW1a,   // [256][128]
                            const short* __restrict__ eW2t,   // [128][256]
                            const float* __restrict__ eb1,
                            const float* __restrict__ eg,
                            const float* __restrict__ ebt,
                            const float* __restrict__ eb2,
                            short* __restrict__ aggBF,        // [N][128] bf16
                            float* __restrict__ edges_out) {
    __shared__ short Abuf[32 * 128];     //  8KB edges tile (bf16, swizzled)
    __shared__ short Sbuf[32 * 256];     // 16KB table-sum, later H
    __shared__ float P[32][4][2];        //  1KB LN partials
    __shared__ int irecv[32];

    const int tid = threadIdx.x;
    const int l = tid & 63, wid = tid >> 6, lg = l >> 4, lo = l & 15;
    const int e0 = blockIdx.x * 32;

    if (tid < 32) {
        int e = e0 + tid; if (e >= E_CNT) e = E_CNT - 1;
        irecv[tid] = receivers[e];
    }

    // ---- stage A: 32 rows x 128 cols; 512 chunks / 256 thr = 2 each ----
    #pragma unroll
    for (int it = 0; it < 2; ++it) {
        int ch = tid + 256 * it;
        int row = ch >> 4, c = (ch & 15) * 8;
        int e = e0 + row; if (e >= E_CNT) e = E_CNT - 1;
        *(bh8*)((char*)Abuf + swz128(row, c)) = pack8(edges + (size_t)e * DD + c);
    }
    // ---- issue table gathers into regs (consumed after GEMM1) ----
    bh8 ts[4], tr[4];
    #pragma unroll
    for (int it = 0; it < 4; ++it) {
        int ch = tid + 256 * it;                 // 1024 chunks of 8 bf16
        int row = ch >> 5, cc = (ch & 31) * 8;
        int e = e0 + row; if (e >= E_CNT) e = E_CNT - 1;
        ts[it] = *(const bh8*)(tabS + (size_t)senders[e] * HH + cc);
        tr[it] = *(const bh8*)(tabR + (size_t)receivers[e] * HH + cc);
    }
    __syncthreads();

    // ---- GEMM1: A[32x128] @ W1a -> acc[32x256]; wave = 32 rows x 64 cols ----
    const int wn = wid;                          // 4 waves = 4 col groups
    fx4 acc[2][4] = {};
    #pragma unroll
    for (int kk = 0; kk < 4; ++kk) {
        int krow = kk * 32 + lg * 8;
        bh8 a[2], b[4];
        #pragma unroll
        for (int i = 0; i < 2; ++i)
            a[i] = *(const bh8*)((char*)Abuf + swz128(16 * i + lo, krow));
        #pragma unroll
        for (int j = 0; j < 4; ++j)
            b[j] = *(const bh8*)(eW1a + (size_t)(wn * 64 + 16 * j + lo) * 128 + krow);
        #pragma unroll
        for (int i = 0; i < 2; ++i)
            #pragma unroll
            for (int j = 0; j < 4; ++j)
                acc[i][j] = mfma16(a[i], b[j], acc[i][j]);
    }

    // ---- combine gathered tables -> Sbuf (paired cvt) ----
    #pragma unroll
    for (int it = 0; it < 4; ++it) {
        int ch = tid + 256 * it;
        int row = ch >> 5, cc = (ch & 31) * 8;
        union { unsigned u[4]; bh8 v; } cv;
        #pragma unroll
        for (int q = 0; q < 4; ++q) {
            float s0 = b2f(ts[it][2 * q])     + b2f(tr[it][2 * q]);
            float s1 = b2f(ts[it][2 * q + 1]) + b2f(tr[it][2 * q + 1]);
            cv.u[q] = f2b2(s0, s1);
        }
        *(bh8*)((char*)Sbuf + swz256(row, cc)) = cv.v;
    }
    __syncthreads();

    // ---- epilogue 1: + table-sum + eb1, LN partials ----
    float eb1c[4], egc[4], ebtc[4];
    #pragma unroll
    for (int j = 0; j < 4; ++j) {
        int col = wn * 64 + 16 * j + lo;
        eb1c[j] = eb1[col]; egc[j] = eg[col]; ebtc[j] = ebt[col];
    }
    #pragma unroll
    for (int i = 0; i < 2; ++i)
        #pragma unroll
        for (int r = 0; r < 4; ++r) {
            int row = 16 * i + lg * 4 + r;
            float s = 0.f, q = 0.f;
            #pragma unroll
            for (int j = 0; j < 4; ++j) {
                int col = wn * 64 + 16 * j + lo;
                float v = acc[i][j][r] + eb1c[j] +
                          b2f(*(const short*)((char*)Sbuf + swz256(row, col)));
                acc[i][j][r] = v;
                s += v; q += v * v;
            }
            #pragma unroll
            for (int m = 1; m < 16; m <<= 1) {
                s += __shfl_xor(s, m);
                q += __shfl_xor(q, m);
            }
            if (lo == 0) { P[row][wn][0] = s; P[row][wn][1] = q; }
        }
    __syncthreads();   // Sbuf reads done; partials visible

    // ---- epilogue 2: LN + relu -> H into Sbuf (paired cvt) ----
    #pragma unroll
    for (int i = 0; i < 2; ++i)
        #pragma unroll
        for (int r = 0; r < 4; ++r) {
            int row = 16 * i + lg * 4 + r;
            float s = P[row][0][0] + P[row][1][0] + P[row][2][0] + P[row][3][0];
            float q = P[row][0][1] + P[row][1][1] + P[row][2][1] + P[row][3][1];
            float mean = s * (1.0f / 256.0f);
            float var = q * (1.0f / 256.0f) - mean * mean;
            float rstd = rsqrtf(var + LN_EPS);
            float hv[4];
            #pragma unroll
            for (int j = 0; j < 4; ++j) {
                float v = (acc[i][j][r] - mean) * rstd * egc[j] + ebtc[j];
                hv[j] = fmaxf(v, 0.0f);
            }
            unsigned p01 = f2b2(hv[0], hv[1]);
            unsigned p23 = f2b2(hv[2], hv[3]);
            *(short*)((char*)Sbuf + swz256(row, wn * 64 +  0 + lo)) = (short)p01;
            *(short*)((char*)Sbuf + swz256(row, wn * 64 + 16 + lo)) = (short)(p01 >> 16);
            *(short*)((char*)Sbuf + swz256(row, wn * 64 + 32 + lo)) = (short)p23;
            *(short*)((char*)Sbuf + swz256(row, wn * 64 + 48 + lo)) = (short)(p23 >> 16);
        }
    __syncthreads();

    // ---- GEMM2: H[32x256] @ eW2 -> [32x128]; wave = 16 rows x 64 cols ----
    const int wm2 = wid >> 1, wn2 = wid & 1;
    fx4 acc2[4] = {};
    #pragma unroll
    for (int kk = 0; kk < 8; ++kk) {
        int krow = kk * 32 + lg * 8;
        bh8 a = *(const bh8*)((char*)Sbuf + swz256(wm2 * 16 + lo, krow));
        #pragma unroll
        for (int j = 0; j < 4; ++j) {
            bh8 b = *(const bh8*)(eW2t + (size_t)(wn2 * 64 + 16 * j + lo) * HH + krow);
            acc2[j] = mfma16(a, b, acc2[j]);
        }
    }
    float eb2c[4];
    #pragma unroll
    for (int j = 0; j < 4; ++j) eb2c[j] = eb2[wn2 * 64 + 16 * j + lo];
    #pragma unroll
    for (int r = 0; r < 4; ++r) {
        int row = wm2 * 16 + lg * 4 + r;
        int e = e0 + row;
        int rcv = irecv[row];
        #pragma unroll
        for (int j = 0; j < 4; ++j) {
            int col = wn2 * 64 + 16 * j + lo;
            float upd = acc2[j][r] + eb2c[j];
            // pair-exchange for packed atomic: adjacent cols sit in lane^1
            float par = __shfl_xor(upd, 1);
            if (e < E_CNT) {
                float res = b2f(*(const short*)((char*)Abuf + swz128(row, col)));
                edges_out[(size_t)e * DD + col] = upd + res;
                if ((lo & 1) == 0) {
                    unsigned pk = f2b2(upd, par);   // one v_cvt_pk_bf16_f32
                    short* p = aggBF + (size_t)rcv * DD + col;
                    asm volatile("global_atomic_pk_add_bf16 %0, %1, off"
                                 :: "v"(p), "v"(pk) : "memory");
                }
            }
        }
    }
}

// ---------------------------------------------------------------------------
// Node kernel: nx=[nodes|aggBF] -> GEMM1 (K=256) -> LN/relu -> GEMM2 + nb2 + nodes
// ---------------------------------------------------------------------------
__launch_bounds__(512, 2)
__global__ void node_kernel(const float* __restrict__ nodes,
                            const short* __restrict__ aggBF,  // [N][128] bf16
                            const short* __restrict__ nW1t,   // [256][256]
                            const short* __restrict__ nW2t,   // [128][256]
                            const float* __restrict__ nb1,
                            const float* __restrict__ ng,
                            const float* __restrict__ nbt,
                            const float* __restrict__ nb2,
                            float* __restrict__ nodes_out) {
    __shared__ char X[64 * 256 * 2];
    __shared__ float P[64][4][2];

    const int tid = threadIdx.x;
    const int l = tid & 63, wid = tid >> 6;
    const int n0 = blockIdx.x * 64;

    #pragma unroll
    for (int it = 0; it < 4; ++it) {
        int c = tid + 512 * it;
        int row = c >> 5, cc = (c & 31) * 8;
        int n = n0 + row; if (n >= N_CNT) n = N_CNT - 1;
        bh8 v;
        if (cc < DD) v = pack8(nodes + (size_t)n * DD + cc);
        else         v = *(const bh8*)(aggBF + (size_t)n * DD + (cc - DD));
        *(bh8*)(X + swz256(row, cc)) = v;
    }
    __syncthreads();

    const int wm = wid >> 2, wn = wid & 3;
    fx4 acc[2][4] = {};
    #pragma unroll
    for (int kk = 0; kk < 8; ++kk) {
        int krow = kk * 32 + (l >> 4) * 8;
        bh8 a[2], b[4];
        #pragma unroll
        for (int i = 0; i < 2; ++i)
            a[i] = *(const bh8*)(X + swz256(wm * 32 + 16 * i + (l & 15), krow));
        #pragma unroll
        for (int j = 0; j < 4; ++j)
            b[j] = *(const bh8*)(nW1t + (size_t)(wn * 64 + 16 * j + (l & 15)) * 256 + krow);
        #pragma unroll
        for (int i = 0; i < 2; ++i)
            #pragma unroll
            for (int j = 0; j < 4; ++j)
                acc[i][j] = mfma16(a[i], b[j], acc[i][j]);
    }
    __syncthreads();

    float nb1c[4], ngc[4], nbtc[4];
    #pragma unroll
    for (int j = 0; j < 4; ++j) {
        int col = wn * 64 + 16 * j + (l & 15);
        nb1c[j] = nb1[col]; ngc[j] = ng[col]; nbtc[j] = nbt[col];
    }
    #pragma unroll
    for (int i = 0; i < 2; ++i)
        #pragma unroll
        for (int r = 0; r < 4; ++r) {
            int row = wm * 32 + 16 * i + (l >> 4) * 4 + r;
            float s = 0.f, q = 0.f;
            #pragma unroll
            for (int j = 0; j < 4; ++j) {
                float v = acc[i][j][r] + nb1c[j];
                acc[i][j][r] = v;
                s += v; q += v * v;
            }
            #pragma unroll
            for (int m = 1; m < 16; m <<= 1) {
                s += __shfl_xor(s, m);
                q += __shfl_xor(q, m);
            }
            if ((l & 15) == 0) { P[row][wn][0] = s; P[row][wn][1] = q; }
        }
    __syncthreads();

    #pragma unroll
    for (int i = 0; i < 2; ++i)
        #pragma unroll
        for (int r = 0; r < 4; ++r) {
            int row = wm * 32 + 16 * i + (l >> 4) * 4 + r;
            float s = P[row][0][0] + P[row][1][0] + P[row][2][0] + P[row][3][0];
            float q = P[row][0][1] + P[row][1][1] + P[row][2][1] + P[row][3][1];
            float mean = s * (1.0f / 256.0f);
            float var = q * (1.0f / 256.0f) - mean * mean;
            float rstd = rsqrtf(var + LN_EPS);
            float hv[4];
            #pragma unroll
            for (int j = 0; j < 4; ++j) {
                float v = (acc[i][j][r] - mean) * rstd * ngc[j] + nbtc[j];
                hv[j] = fmaxf(v, 0.0f);
            }
            unsigned p01 = f2b2(hv[0], hv[1]);
            unsigned p23 = f2b2(hv[2], hv[3]);
            int c0 = wn * 64 + (l & 15);
            *(short*)(X + swz256(row, c0 +  0)) = (short)p01;
            *(short*)(X + swz256(row, c0 + 16)) = (short)(p01 >> 16);
            *(short*)(X + swz256(row, c0 + 32)) = (short)p23;
            *(short*)(X + swz256(row, c0 + 48)) = (short)(p23 >> 16);
        }
    __syncthreads();

    const int wm2 = wid >> 1, wn2 = wid & 1;
    fx4 acc2[4] = {};
    #pragma unroll
    for (int kk = 0; kk < 8; ++kk) {
        int krow = kk * 32 + (l >> 4) * 8;
        bh8 a = *(const bh8*)(X + swz256(wm2 * 16 + (l & 15), krow));
        #pragma unroll
        for (int j = 0; j < 4; ++j) {
            bh8 b = *(const bh8*)(nW2t + (size_t)(wn2 * 64 + 16 * j + (l & 15)) * 256 + krow);
            acc2[j] = mfma16(a, b, acc2[j]);
        }
    }
    float nb2c[4];
    #pragma unroll
    for (int j = 0; j < 4; ++j) nb2c[j] = nb2[wn2 * 64 + 16 * j + (l & 15)];
    #pragma unroll
    for (int r = 0; r < 4; ++r) {
        int row = wm2 * 16 + (l >> 4) * 4 + r;
        int n = n0 + row;
        if (n < N_CNT) {
            #pragma unroll
            for (int j = 0; j < 4; ++j) {
                int col = wn2 * 64 + 16 * j + (l & 15);
                nodes_out[(size_t)n * DD + col] =
                    acc2[j][r] + nb2c[j] + nodes[(size_t)n * DD + col];
            }
        }
    }
}

// ---------------------------------------------------------------------------
extern "C" void kernel_launch(void* const* d_in, const int* in_sizes, int n_in,
                              void* d_out, int out_size, void* d_ws, size_t ws_size,
                              hipStream_t stream) {
    const float* nodes = (const float*)d_in[0];
    const float* edges = (const float*)d_in[1];
    const int* senders = (const int*)d_in[2];
    const int* receivers = (const int*)d_in[3];
    const float* eW1 = (const float*)d_in[4];
    const float* eb1 = (const float*)d_in[5];
    const float* eg  = (const float*)d_in[6];
    const float* ebt = (const float*)d_in[7];
    const float* eW2 = (const float*)d_in[8];
    const float* eb2 = (const float*)d_in[9];
    const float* nW1 = (const float*)d_in[10];
    const float* nb1 = (const float*)d_in[11];
    const float* ng  = (const float*)d_in[12];
    const float* nbt = (const float*)d_in[13];
    const float* nW2 = (const float*)d_in[14];
    const float* nb2 = (const float*)d_in[15];

    char* ws = (char*)d_ws;
    short* aggBF = (short*)(ws + 0);            // 12,800,000 B [N][128] bf16
    short* eW1t  = (short*)(ws + 12800000);     //    196,608 B [256][384]
    short* eW2t  = (short*)(ws + 12996608);     //     65,536 B [128][256]
    short* nW1t  = (short*)(ws + 13062144);     //    131,072 B [256][256]
    short* nW2t  = (short*)(ws + 13193216);     //     65,536 B [128][256]
    short* eW1a  = (short*)(ws + 13258752);     //     65,536 B [256][128]
    short* tabS  = (short*)(ws + 13324288);     // 25,600,000 B [N][256]
    short* tabR  = (short*)(ws + 38924288);     // 25,600,000 B [N][256]

    float* nodes_out = (float*)d_out;
    float* edges_out = nodes_out + (size_t)N_CNT * DD;

    hipMemsetAsync(aggBF, 0, (size_t)N_CNT * DD * sizeof(short), stream);

    wtrans<<<(384 * 256 + 255) / 256, 256, 0, stream>>>(eW1, eW1t, 384, 256);
    wtrans<<<(256 * 128 + 255) / 256, 256, 0, stream>>>(eW2, eW2t, 256, 128);
    wtrans<<<(256 * 256 + 255) / 256, 256, 0, stream>>>(nW1, nW1t, 256, 256);
    wtrans<<<(256 * 128 + 255) / 256, 256, 0, stream>>>(nW2, nW2t, 256, 128);
    wtransA<<<(256 * 128 + 255) / 256, 256, 0, stream>>>(eW1, eW1a);

    table_kernel<<<(N_CNT + 127) / 128, 512, 0, stream>>>(nodes, eW1t, tabS, tabR);

    edge_kernel<<<(E_CNT + 31) / 32, 256, 0, stream>>>(
        edges, senders, receivers, tabS, tabR, eW1a, eW2t,
        eb1, eg, ebt, eb2, aggBF, edges_out);

    node_kernel<<<(N_CNT + 63) / 64, 512, 0, stream>>>(
        nodes, aggBF, nW1t, nW2t, nb1, ng, nbt, nb2, nodes_out);
}